// Round 1
// baseline (254.955 us; speedup 1.0000x reference)
//
#include <hip/hip_runtime.h>

#define DHW   65536
#define NCH   256
#define NNODE 7
#define NHID  128
#define NBATCH 2

// ---------------------------------------------------------------------------
// Prep kernel: new_weight[b,n,c] = sum_h inp[b,n,h]*weight[h,c], stored
// transposed+padded as nwt[b][c][8]; n2[b,n] = sum_h inp[b,n,h]*nfh[h].
// Grid: 14 blocks (b*7+n), 256 threads (one per c).
// ---------------------------------------------------------------------------
__global__ void prep_kernel(const float* __restrict__ inp,
                            const float* __restrict__ nfh,
                            const float* __restrict__ weight,
                            float* __restrict__ nwt,   // [2][256][8]
                            float* __restrict__ n2g)   // [2][8]
{
    const int bn = blockIdx.x;
    const int b  = bn / NNODE;
    const int n  = bn % NNODE;
    const int t  = threadIdx.x;            // c index
    const float* ih = inp + (b * NNODE + n) * NHID;

    float acc = 0.f;
    #pragma unroll 8
    for (int h = 0; h < NHID; ++h)
        acc = fmaf(ih[h], weight[h * NCH + t], acc);
    nwt[(b * NCH + t) * 8 + n] = acc;

    __shared__ float red[NHID];
    if (t < NHID) red[t] = ih[t] * nfh[t];
    __syncthreads();
    for (int s = NHID / 2; s > 0; s >>= 1) {
        if (t < s) red[t] += red[t + s];
        __syncthreads();
    }
    if (t == 0) n2g[b * 8 + n] = red[0];
}

// ---------------------------------------------------------------------------
// Main kernel: one thread per spatial point p.
// Phase 1: stream 256 channels of res_feature -> 7 scores. Softmax in-reg.
// Phase 2: stream 256 output channels. Single read + single write of 128 MiB.
// Grid: 512 blocks x 256 threads (2 blocks/CU -> 8 waves/CU).
// ---------------------------------------------------------------------------
__global__ __launch_bounds__(256, 2)
void main_kernel(const float* __restrict__ rf,    // [2][256][65536]
                 const float* __restrict__ w1,    // [256][7]
                 const float* __restrict__ nwt,   // [2][256][8]
                 const float* __restrict__ n2g,   // [2][8]
                 float* __restrict__ out)         // [2][256][65536]
{
    __shared__ float4 w1_lds[NCH][2];   // [c][n-padded-to-8]
    __shared__ float4 nw_lds[NCH][2];   // [c][n-padded-to-8]
    __shared__ float  n2_lds[8];

    const int t   = threadIdx.x;
    const int blk = blockIdx.x;          // 0..511
    const int b   = blk >> 8;
    const int p   = ((blk & 255) << 8) + t;

    // Stage W1 (pad 7->8). 7 KiB, one-time, L2-cached across blocks.
    {
        const float* src = w1 + t * NNODE;
        float* dst = (float*)&w1_lds[t][0];
        #pragma unroll
        for (int n = 0; n < NNODE; ++n) dst[n] = src[n];
        dst[7] = 0.f;
    }
    // Stage new_weight^T (coalesced float4).
    {
        const float4* src = (const float4*)(nwt + b * NCH * 8);
        float4* dst = &nw_lds[0][0];
        dst[t]       = src[t];
        dst[t + 256] = src[t + 256];
    }
    if (t < 8) n2_lds[t] = (t < NNODE) ? n2g[b * 8 + t] : 0.f;
    __syncthreads();

    // ---- Phase 1: scores ------------------------------------------------
    const float* rp = rf + ((size_t)(b * NCH) << 16) + p;
    float s0 = n2_lds[0], s1 = n2_lds[1], s2 = n2_lds[2], s3 = n2_lds[3];
    float s4 = n2_lds[4], s5 = n2_lds[5], s6 = n2_lds[6];
    #pragma unroll 8
    for (int c = 0; c < NCH; ++c) {
        float v = rp[(size_t)c << 16];
        float4 wa = w1_lds[c][0];
        float4 wb = w1_lds[c][1];
        s0 = fmaf(v, wa.x, s0);
        s1 = fmaf(v, wa.y, s1);
        s2 = fmaf(v, wa.z, s2);
        s3 = fmaf(v, wa.w, s3);
        s4 = fmaf(v, wb.x, s4);
        s5 = fmaf(v, wb.y, s5);
        s6 = fmaf(v, wb.z, s6);
    }

    // ---- Softmax over 7 nodes ------------------------------------------
    float m = fmaxf(fmaxf(fmaxf(s0, s1), fmaxf(s2, s3)),
                    fmaxf(fmaxf(s4, s5), s6));
    float e0 = __expf(s0 - m), e1 = __expf(s1 - m), e2 = __expf(s2 - m);
    float e3 = __expf(s3 - m), e4 = __expf(s4 - m), e5 = __expf(s5 - m);
    float e6 = __expf(s6 - m);
    float inv = 1.0f / (e0 + e1 + e2 + e3 + e4 + e5 + e6);
    float a0 = e0 * inv, a1 = e1 * inv, a2 = e2 * inv, a3 = e3 * inv;
    float a4 = e4 * inv, a5 = e5 * inv, a6 = e6 * inv;

    // ---- Phase 2: outputs ----------------------------------------------
    float* op = out + ((size_t)(b * NCH) << 16) + p;
    #pragma unroll 8
    for (int c = 0; c < NCH; ++c) {
        float4 na = nw_lds[c][0];
        float4 nb = nw_lds[c][1];
        float o = a0 * na.x + a1 * na.y + a2 * na.z + a3 * na.w
                + a4 * nb.x + a5 * nb.y + a6 * nb.z;
        op[(size_t)c << 16] = fmaxf(o, 0.f);
    }
}

extern "C" void kernel_launch(void* const* d_in, const int* in_sizes, int n_in,
                              void* d_out, int out_size, void* d_ws, size_t ws_size,
                              hipStream_t stream) {
    const float* inp = (const float*)d_in[0];   // (1,2,7,128)
    const float* rf  = (const float*)d_in[1];   // (2,256,16,64,64)
    const float* w1  = (const float*)d_in[2];   // (256,7)
    const float* nfh = (const float*)d_in[3];   // (128,1)
    const float* wgt = (const float*)d_in[4];   // (128,256)
    float* out = (float*)d_out;

    float* nwt = (float*)d_ws;                  // [2][256][8] = 16 KiB
    float* n2g = nwt + NBATCH * NCH * 8;        // [2][8]

    prep_kernel<<<NBATCH * NNODE, 256, 0, stream>>>(inp, nfh, wgt, nwt, n2g);
    main_kernel<<<NBATCH * 256, 256, 0, stream>>>(rf, w1, nwt, n2g, out);
}